// Round 6
// baseline (439.835 us; speedup 1.0000x reference)
//
#include <hip/hip_runtime.h>
#include <math.h>

#define NB 2
#define NN 2048
#define HIDDEN 2048
#define NHEAD 16
#define DHEAD 128

typedef __attribute__((ext_vector_type(8))) short bf16x8;
typedef __attribute__((ext_vector_type(4))) float floatx4;

static __device__ __forceinline__ short f2bf(float f) {
    union { float f; unsigned u; } v; v.f = f;
    unsigned r = v.u + 0x7fffu + ((v.u >> 16) & 1u);
    return (short)(r >> 16);
}
static __device__ __forceinline__ void gload_lds16(const short* g, short* l) {
    __builtin_amdgcn_global_load_lds(
        (const __attribute__((address_space(1))) void*)g,
        (__attribute__((address_space(3))) void*)l, 16, 0, 0);
}

// ---------------------------------------------------------------------------
// cast 3 fp32 arrays to bf16
// ---------------------------------------------------------------------------
__global__ __launch_bounds__(256) void cast_bf16_3(
    const float* __restrict__ a, const float* __restrict__ b, const float* __restrict__ c,
    short* __restrict__ oa, short* __restrict__ ob, short* __restrict__ oc,
    int n4a, int n4b, int n4c)
{
    int i = blockIdx.x * 256 + threadIdx.x;
    const float* s; short* d; int j;
    if (i < n4a) { s = a; d = oa; j = i; }
    else if (i < n4a + n4b) { s = b; d = ob; j = i - n4a; }
    else if (i < n4a + n4b + n4c) { s = c; d = oc; j = i - n4a - n4b; }
    else return;
    float4 v = ((const float4*)s)[j];
    short4 o;
    o.x = f2bf(v.x); o.y = f2bf(v.y); o.z = f2bf(v.z); o.w = f2bf(v.w);
    ((short4*)d)[j] = o;
}

// ---------------------------------------------------------------------------
// QKV GEMM, 256x256 / BK=64 / 8 waves (2Mx4N), m201-discipline 4-phase:
// each phase = {ds_read frag subtile, STAGE one 2-load unit} -> barrier ->
// setprio(1) 16xMFMA setprio(0) -> [vmcnt(4) where needed] -> barrier.
// Reads issue pre-barrier (latency hides under barrier wait); MFMA clusters
// run in lockstep (role-split makes setprio effective); counted vmcnt never
// 0 in loop.
// Quadrants / frag lifetimes (aLo=A m0-3, aHi=A m4-7, b01=B n0-1, b23=n2-3):
//   P0: read aLo,b01; stage U0; MFMA (m0-3 x n0-1); vmcnt(4); bar
//   P1: read b23;     stage U1; MFMA (m0-3 x n2-3); vmcnt(4); bar
//   P2: read aHi;     stage U3; MFMA (m4-7 x n2-3);            bar
//   P3:               stage U2; MFMA (m4-7 x n0-1); vmcnt(4); bar
// Stage units (2x gload_lds each, issue order = consumption order):
//   U0 = A rows {0-63,128-191} (m0-3 of both wr), U1 = B rows 0-127,
//   U3 = B rows 128-255, U2 = A rows {64-127,192-255}.
// Ledger: vmcnt(4) leaves the last 2 issued units outstanding ->
//   P0-end validates U3(t) (read @P1), P1-end validates U2(t) (read @P2),
//   P3-end validates U0,U1(t+1) (read @P0).  >=2-phase slack covers HBM.
// LDS 128 KB dbuf, row-major 128 B rows, 16B-chunk XOR swizzle j^=(row&7)
// (inverse-swizzled global source + linear gload_lds dest + swizzled read).
// B-frag col(n) = n*64 + wc*16 + l15  (RoPE pairs (d,d+64) in one wave).
// Exit: vmcnt(0) drain before epilogue (LDS-DMA outstanding at endpgm
// writes LDS after retirement -> queue wedge).
// Grid (24,16) natural order: consecutive blocks share the A panel in L2.
// ---------------------------------------------------------------------------
__global__ __launch_bounds__(512, 2) void gemm_qkv_256(
    const short* __restrict__ A, const short* __restrict__ Bw,
    const float* __restrict__ cosT, const float* __restrict__ sinT,
    short* __restrict__ Qp, short* __restrict__ Kp, short* __restrict__ Vtp)
{
    __shared__ __align__(16) short AB[65536];   // 128 KB

    const int tid = threadIdx.x;
    const int w = tid >> 6;
    const int l = tid & 63;
    const int quad = l >> 4;
    const int l15 = l & 15;
    const int wr = w >> 2;          // 0..1  M half
    const int wc = w & 3;           // 0..3  N 16-col band
    const int bx = blockIdx.x;
    const int bm = blockIdx.y * 256;
    const int bn = bx * 256;
    const int K = HIDDEN;

    // ---- staging: 8 loads, issue order U0a,U0b,U1a,U1b,U3a,U3b,U2a,U2b
    const int row64 = tid >> 3;                  // 0..63
    const int jj = (tid & 7) ^ (row64 & 7);      // inverse swizzle on source
    const int coff = jj * 8;
    const short* src[8];
    int ldst[8];
    src[0] = A  + (size_t)(bm + row64) * K + coff;        ldst[0] = 0     + tid * 16;  // A 0-63
    src[1] = A  + (size_t)(bm + 128 + row64) * K + coff;  ldst[1] = 16384 + tid * 16;  // A 128-191
    src[2] = Bw + (size_t)(bn + row64) * K + coff;        ldst[2] = 32768 + tid * 16;  // B 0-63
    src[3] = Bw + (size_t)(bn + 64 + row64) * K + coff;   ldst[3] = 40960 + tid * 16;  // B 64-127
    src[4] = Bw + (size_t)(bn + 128 + row64) * K + coff;  ldst[4] = 49152 + tid * 16;  // B 128-191
    src[5] = Bw + (size_t)(bn + 192 + row64) * K + coff;  ldst[5] = 57344 + tid * 16;  // B 192-255
    src[6] = A  + (size_t)(bm + 64 + row64) * K + coff;   ldst[6] = 8192  + tid * 16;  // A 64-127
    src[7] = A  + (size_t)(bm + 192 + row64) * K + coff;  ldst[7] = 24576 + tid * 16;  // A 192-255

    // ---- frag-read invariants (frag row&7 == l15&7 everywhere)
    const int xj = l15 & 7;
    const int jq0 = ((0 * 4 + quad) ^ xj) * 16;   // kc=0 chunk byte off
    const int jq1 = ((1 * 4 + quad) ^ xj) * 16;   // kc=1
    const int arow = (wr * 128 + l15) * 128;      // + m*2048
    const int brow = 32768 + (wc * 16 + l15) * 128;   // + n*8192

    floatx4 acc[8][4];
#pragma unroll
    for (int i = 0; i < 8; ++i)
#pragma unroll
        for (int j = 0; j < 4; ++j) acc[i][j] = (floatx4){0.f, 0.f, 0.f, 0.f};

    // ---- prologue: stage tile 0 (U0,U1,U3,U2); validate U0,U1
#pragma unroll
    for (int i = 0; i < 8; ++i)
        gload_lds16(src[i], (short*)((char*)AB + ldst[i]));
    asm volatile("s_waitcnt vmcnt(4)" ::: "memory");
    __builtin_amdgcn_s_barrier();

#define STAGE(i) gload_lds16(src[i] + kpf, (short*)((char*)AB + ldst[i] + so))
#define MFMA(d, x, y) d = __builtin_amdgcn_mfma_f32_16x16x32_bf16(x, y, d, 0, 0, 0)

    const int NT = K / 64;   // 32
#pragma unroll 1
    for (int t = 0; t < NT; ++t) {
        const int co = (t & 1) << 16;       // compute buffer
        const int so = co ^ 65536;          // stage buffer
        int kpf = (t + 1) * 64;
        if (kpf == K) kpf = 0;              // wrap: dummy prefetch (drained below)

        bf16x8 aLo[4][2], aHi[4][2], b01[2][2], b23[2][2];

        // ---------------- P0: read aLo,b01; stage U0; MFMA m0-3 x n0-1
#pragma unroll
        for (int m = 0; m < 4; ++m) {
            aLo[m][0] = *(const bf16x8*)((const char*)AB + co + arow + m * 2048 + jq0);
            aLo[m][1] = *(const bf16x8*)((const char*)AB + co + arow + m * 2048 + jq1);
        }
#pragma unroll
        for (int n = 0; n < 2; ++n) {
            b01[n][0] = *(const bf16x8*)((const char*)AB + co + brow + n * 8192 + jq0);
            b01[n][1] = *(const bf16x8*)((const char*)AB + co + brow + n * 8192 + jq1);
        }
        STAGE(0); STAGE(1);
        __builtin_amdgcn_s_barrier();
        __builtin_amdgcn_s_setprio(1);
#pragma unroll
        for (int m = 0; m < 4; ++m)
#pragma unroll
            for (int n = 0; n < 2; ++n) {
                MFMA(acc[m][n], aLo[m][0], b01[n][0]);
                MFMA(acc[m][n], aLo[m][1], b01[n][1]);
            }
        __builtin_amdgcn_s_setprio(0);
        asm volatile("s_waitcnt vmcnt(4)" ::: "memory");   // U3(t) valid
        __builtin_amdgcn_s_barrier();

        // ---------------- P1: read b23; stage U1; MFMA m0-3 x n2-3
#pragma unroll
        for (int n = 0; n < 2; ++n) {
            b23[n][0] = *(const bf16x8*)((const char*)AB + co + brow + 16384 + n * 8192 + jq0);
            b23[n][1] = *(const bf16x8*)((const char*)AB + co + brow + 16384 + n * 8192 + jq1);
        }
        STAGE(2); STAGE(3);
        __builtin_amdgcn_s_barrier();
        __builtin_amdgcn_s_setprio(1);
#pragma unroll
        for (int m = 0; m < 4; ++m)
#pragma unroll
            for (int n = 0; n < 2; ++n) {
                MFMA(acc[m][2 + n], aLo[m][0], b23[n][0]);
                MFMA(acc[m][2 + n], aLo[m][1], b23[n][1]);
            }
        __builtin_amdgcn_s_setprio(0);
        asm volatile("s_waitcnt vmcnt(4)" ::: "memory");   // U2(t) valid
        __builtin_amdgcn_s_barrier();

        // ---------------- P2: read aHi; stage U3; MFMA m4-7 x n2-3
#pragma unroll
        for (int m = 0; m < 4; ++m) {
            aHi[m][0] = *(const bf16x8*)((const char*)AB + co + arow + (4 + m) * 2048 + jq0);
            aHi[m][1] = *(const bf16x8*)((const char*)AB + co + arow + (4 + m) * 2048 + jq1);
        }
        STAGE(4); STAGE(5);
        __builtin_amdgcn_s_barrier();
        __builtin_amdgcn_s_setprio(1);
#pragma unroll
        for (int m = 0; m < 4; ++m)
#pragma unroll
            for (int n = 0; n < 2; ++n) {
                MFMA(acc[4 + m][2 + n], aHi[m][0], b23[n][0]);
                MFMA(acc[4 + m][2 + n], aHi[m][1], b23[n][1]);
            }
        __builtin_amdgcn_s_setprio(0);
        __builtin_amdgcn_s_barrier();

        // ---------------- P3: stage U2; MFMA m4-7 x n0-1; late vmcnt
        STAGE(6); STAGE(7);
        __builtin_amdgcn_s_barrier();
        __builtin_amdgcn_s_setprio(1);
#pragma unroll
        for (int m = 0; m < 4; ++m)
#pragma unroll
            for (int n = 0; n < 2; ++n) {
                MFMA(acc[4 + m][n], aHi[m][0], b01[n][0]);
                MFMA(acc[4 + m][n], aHi[m][1], b01[n][1]);
            }
        __builtin_amdgcn_s_setprio(0);
        asm volatile("s_waitcnt vmcnt(4)" ::: "memory");   // U0,U1(t+1) valid
        __builtin_amdgcn_s_barrier();
    }
#undef STAGE
#undef MFMA

    // ---- drain wrap prefetches while LDS is still owned
    asm volatile("s_waitcnt vmcnt(0)" ::: "memory");

    // ---- epilogue: RoPE q/k + scatter, V^T.  col(n) = n*64 + wc*16 + l15
    const int which = bx >> 3;                 // 0=q 1=k 2=v
    const int hpair = (bx & 7) * 2;
    const float qsc = (which == 0) ? 0.12751791525f : 1.0f;  // 1/sqrt(128)*log2e

#pragma unroll
    for (int m = 0; m < 8; ++m) {
#pragma unroll
        for (int reg = 0; reg < 4; ++reg) {
            int gm = bm + wr * 128 + m * 16 + quad * 4 + reg;
            int b = gm >> 11, nseq = gm & (NN - 1);
            if (which == 2) {
#pragma unroll
                for (int n = 0; n < 4; ++n) {
                    int bh = b * NHEAD + hpair + (n >> 1);
                    int d = (n & 1) * 64 + wc * 16 + l15;
                    Vtp[((size_t)bh * DHEAD + d) * NN + nseq] = f2bf(acc[m][n][reg]);
                }
            } else {
                int d0 = wc * 16 + l15;        // < 64
                float c = cosT[(size_t)nseq * DHEAD + d0];
                float s = sinT[(size_t)nseq * DHEAD + d0];
#pragma unroll
                for (int hb = 0; hb < 2; ++hb) {
                    int bh = b * NHEAD + hpair + hb;
                    short* dst = (which == 0 ? Qp : Kp) + ((size_t)bh * NN + nseq) * DHEAD;
                    float e0 = acc[m][hb * 2 + 0][reg];
                    float e1 = acc[m][hb * 2 + 1][reg];
                    dst[d0]      = f2bf((e0 * c - e1 * s) * qsc);
                    dst[d0 + 64] = f2bf((e1 * c + e0 * s) * qsc);
                }
            }
        }
    }
}

// ---------------------------------------------------------------------------
// bf16 MFMA NT GEMM (kept for the output projection, MODE 1).
// ---------------------------------------------------------------------------
template <int MODE>
__global__ __launch_bounds__(256) void gemm_bf16_nt(
    const short* __restrict__ A, const short* __restrict__ Bw,
    const float* __restrict__ cosT, const float* __restrict__ sinT,
    short* __restrict__ Qp, short* __restrict__ Kp, short* __restrict__ Vtp,
    float* __restrict__ Cp, int M, int N, int K)
{
    __shared__ __align__(16) short AB[1280 * 8];   // 20.5 KB

    const int tid = threadIdx.x;
    const int w = tid >> 6;
    const int l = tid & 63;
    const int quad = l >> 4;
    const int l15 = l & 15;
    const int bm = blockIdx.y * 128;
    const int bn = blockIdx.x * 128;

    const int wm = (w & 1) * 64;
    const int wn2 = w >> 1;

    const short* gptr[5];
    short* lptr[5];
#pragma unroll
    for (int r5 = 0; r5 < 5; ++r5) {
        int s = r5 * 256 + tid;
        int m = (s < 640) ? s : s - 640;
        int row = m / 5;
        int ch = m - row * 5;
        if (ch == 4) ch = 0;
        gptr[r5] = ((s < 640) ? (A + (size_t)(bm + row) * K)
                              : (Bw + (size_t)(bn + row) * K)) + ch * 8;
        lptr[r5] = &AB[s * 8];
    }

    floatx4 acc[4][4];
#pragma unroll
    for (int i = 0; i < 4; ++i)
#pragma unroll
        for (int j = 0; j < 4; ++j) acc[i][j] = (floatx4){0.f, 0.f, 0.f, 0.f};

    for (int k0 = 0; k0 < K; k0 += 32) {
        __syncthreads();
#pragma unroll
        for (int r5 = 0; r5 < 5; ++r5)
            gload_lds16(gptr[r5] + k0, lptr[r5]);
        __syncthreads();

        bf16x8 af[4], bf[4];
#pragma unroll
        for (int i = 0; i < 4; ++i)
            af[i] = *(const bf16x8*)&AB[((wm + i * 16 + l15) * 5 + quad) * 8];
#pragma unroll
        for (int j = 0; j < 4; ++j) {
            int col = wn2 * 32 + (j & 1) * 16 + ((j >> 1) << 6);
            bf[j] = *(const bf16x8*)&AB[(640 + (col + l15) * 5 + quad) * 8];
        }
#pragma unroll
        for (int i = 0; i < 4; ++i)
#pragma unroll
            for (int j = 0; j < 4; ++j)
                acc[i][j] = __builtin_amdgcn_mfma_f32_16x16x32_bf16(af[i], bf[j], acc[i][j], 0, 0, 0);
    }

    if (MODE == 1) {
#pragma unroll
        for (int i = 0; i < 4; ++i) {
#pragma unroll
            for (int reg = 0; reg < 4; ++reg) {
                int row = bm + wm + i * 16 + quad * 4 + reg;
                float* crow = Cp + (size_t)row * N + bn;
#pragma unroll
                for (int j = 0; j < 4; ++j)
                    crow[wn2 * 32 + (j & 1) * 16 + ((j >> 1) << 6) + l15] = acc[i][j][reg];
            }
        }
    } else {
        const int which = bn >> 11;
        const int head = (bn >> 7) & (NHEAD - 1);
        const float qsc = (which == 0) ? 0.12751791525f : 1.0f;
#pragma unroll
        for (int i = 0; i < 4; ++i) {
#pragma unroll
            for (int reg = 0; reg < 4; ++reg) {
                int m = bm + wm + i * 16 + quad * 4 + reg;
                int b = m >> 11, n = m & (NN - 1);
                int bh = b * NHEAD + head;
                if (which == 2) {
#pragma unroll
                    for (int j = 0; j < 4; ++j) {
                        int d = wn2 * 32 + (j & 1) * 16 + ((j >> 1) << 6) + l15;
                        Vtp[((size_t)bh * DHEAD + d) * NN + n] = f2bf(acc[i][j][reg]);
                    }
                } else {
                    short* dst = (which == 0 ? Qp : Kp) + ((size_t)bh * NN + n) * DHEAD;
#pragma unroll
                    for (int j = 0; j < 2; ++j) {
                        int d0 = wn2 * 32 + j * 16 + l15;
                        float c = cosT[(size_t)n * DHEAD + d0];
                        float s = sinT[(size_t)n * DHEAD + d0];
                        float e0 = acc[i][j][reg], e1 = acc[i][j + 2][reg];
                        dst[d0]      = f2bf((e0 * c - e1 * s) * qsc);
                        dst[d0 + 64] = f2bf((e1 * c + e0 * s) * qsc);
                    }
                }
            }
        }
    }
}

// ---------------------------------------------------------------------------
// MFMA flash attention, R6: 4 waves x 32 Q-rows = 128 Q-rows/block.
// ---------------------------------------------------------------------------
__global__ __launch_bounds__(256, 2) void attn_mfma(
    const short* __restrict__ Qb, const short* __restrict__ Kb,
    const short* __restrict__ Vt, short* __restrict__ AOb)
{
    __shared__ __align__(16) short Ks[64 * 128];    // 16 KB, swizzle (s&15)^(row&15)
    __shared__ __align__(16) short Vs[128 * 64];    // 16 KB, swizzle (s&7)^(row&7)
    __shared__ __align__(16) short Ps[4][32][72];   // 18.4 KB bf16

    const int tid = threadIdx.x;
    const int w = tid >> 6;
    const int l = tid & 63;
    const int quad = l >> 4;
    const int l15 = l & 15;
    const int bh = blockIdx.y;
    const int qt = blockIdx.x * 128;

    const short* Qg = Qb + (size_t)bh * NN * DHEAD;
    const short* Kg = Kb + (size_t)bh * NN * DHEAD;
    const short* Vg = Vt + (size_t)bh * DHEAD * NN;

    bf16x8 qf[2][4];
#pragma unroll
    for (int mi = 0; mi < 2; ++mi) {
        const short* qrow = Qg + (size_t)(qt + w * 32 + mi * 16 + l15) * DHEAD + quad * 8;
#pragma unroll
        for (int kc = 0; kc < 4; ++kc) qf[mi][kc] = *(const bf16x8*)(qrow + kc * 32);
    }

    floatx4 of[2][8];
#pragma unroll
    for (int mi = 0; mi < 2; ++mi)
#pragma unroll
        for (int dc = 0; dc < 8; ++dc) of[mi][dc] = (floatx4){0.f, 0.f, 0.f, 0.f};
    float ls[2][4] = {{0.f, 0.f, 0.f, 0.f}, {0.f, 0.f, 0.f, 0.f}};

    for (int kt = 0; kt < NN; kt += 64) {
        __syncthreads();
#pragma unroll
        for (int rr = 0; rr < 4; ++rr) {
            int s = (w * 4 + rr) * 64 + l;
            int row = s >> 4;
            int j = (s & 15) ^ (row & 15);
            gload_lds16(Kg + (size_t)(kt + row) * DHEAD + j * 8, &Ks[s * 8]);
        }
#pragma unroll
        for (int rr = 0; rr < 4; ++rr) {
            int s = (w * 4 + rr) * 64 + l;
            int row = s >> 3;
            int c = (s & 7) ^ (row & 7);
            gload_lds16(Vg + (size_t)row * NN + kt + c * 8, &Vs[s * 8]);
        }
        __syncthreads();

        floatx4 sf[2][4];
#pragma unroll
        for (int n16 = 0; n16 < 4; ++n16) {
            bf16x8 kf[4];
            const short* kbase = &Ks[(n16 * 16 + l15) * 128];
#pragma unroll
            for (int kc = 0; kc < 4; ++kc)
                kf[kc] = *(const bf16x8*)&kbase[((4 * kc + quad) ^ l15) * 8];
#pragma unroll
            for (int mi = 0; mi < 2; ++mi) {
                floatx4 acc = (floatx4){0.f, 0.f, 0.f, 0.f};
#pragma unroll
                for (int kc = 0; kc < 4; ++kc)
                    acc = __builtin_amdgcn_mfma_f32_16x16x32_bf16(qf[mi][kc], kf[kc], acc, 0, 0, 0);
                sf[mi][n16] = acc;
            }
        }

#pragma unroll
        for (int mi = 0; mi < 2; ++mi)
#pragma unroll
            for (int n16 = 0; n16 < 4; ++n16)
#pragma unroll
                for (int r = 0; r < 4; ++r) {
                    float p = exp2f(sf[mi][n16][r]);
                    ls[mi][r] += p;
                    Ps[w][mi * 16 + quad * 4 + r][n16 * 16 + l15] = f2bf(p);
                }

        bf16x8 pa[2][2];
#pragma unroll
        for (int mi = 0; mi < 2; ++mi)
#pragma unroll
            for (int kc = 0; kc < 2; ++kc)
                pa[mi][kc] = *(const bf16x8*)&Ps[w][mi * 16 + l15][kc * 32 + quad * 8];

#pragma unroll
        for (int dc = 0; dc < 8; ++dc) {
            int row = dc * 16 + l15;
#pragma unroll
            for (int kc = 0; kc < 2; ++kc) {
                bf16x8 vf = *(const bf16x8*)&Vs[row * 64 + (((kc * 4 + quad) ^ (row & 7)) * 8)];
#pragma unroll
                for (int mi = 0; mi < 2; ++mi)
                    of[mi][dc] = __builtin_amdgcn_mfma_f32_16x16x32_bf16(
                                     pa[mi][kc], vf, of[mi][dc], 0, 0, 0);
            }
        }
    }

    const int b = bh >> 4, h = bh & (NHEAD - 1);
#pragma unroll
    for (int mi = 0; mi < 2; ++mi)
#pragma unroll
        for (int r = 0; r < 4; ++r) {
            float s = ls[mi][r];
            s += __shfl_xor(s, 1, 64);
            s += __shfl_xor(s, 2, 64);
            s += __shfl_xor(s, 4, 64);
            s += __shfl_xor(s, 8, 64);
            float inv = 1.0f / s;
            int row = qt + w * 32 + mi * 16 + quad * 4 + r;
            short* dst = AOb + ((size_t)(b * NN + row)) * HIDDEN + h * DHEAD;
#pragma unroll
            for (int dc = 0; dc < 8; ++dc)
                dst[dc * 16 + l15] = f2bf(of[mi][dc][r] * inv);
        }
}

// ---------------------------------------------------------------------------
extern "C" void kernel_launch(void* const* d_in, const int* in_sizes, int n_in,
                              void* d_out, int out_size, void* d_ws, size_t ws_size,
                              hipStream_t stream)
{
    const float* hs = (const float*)d_in[0];
    const float* cosT = (const float*)d_in[1];
    const float* sinT = (const float*)d_in[2];
    const float* wqkv = (const float*)d_in[3];
    const float* wo = (const float*)d_in[4];
    float* out = (float*)d_out;

    const size_t N_HS = (size_t)NB * NN * HIDDEN;
    const size_t N_WQ = (size_t)3 * HIDDEN * HIDDEN;
    const size_t N_WO = (size_t)HIDDEN * HIDDEN;
    const size_t SZ = (size_t)NB * NHEAD * NN * DHEAD;

    short* Ahs   = (short*)d_ws;
    short* Wqkvb = Ahs + N_HS;
    short* Wob   = Wqkvb + N_WQ;
    short* Qb    = Wob + N_WO;
    short* Kb    = Qb + SZ;
    short* Vtb   = Kb + SZ;
    short* AOb   = Vtb + SZ;

    {
        int n4a = (int)(N_HS / 4), n4b = (int)(N_WQ / 4), n4c = (int)(N_WO / 4);
        int total = n4a + n4b + n4c;
        cast_bf16_3<<<(total + 255) / 256, 256, 0, stream>>>(
            hs, wqkv, wo, Ahs, Wqkvb, Wob, n4a, n4b, n4c);
    }
    {
        dim3 grid(3 * HIDDEN / 256, NB * NN / 256);   // (24, 16)
        gemm_qkv_256<<<grid, 512, 0, stream>>>(
            Ahs, Wqkvb, cosT, sinT, Qb, Kb, Vtb);
    }
    {
        dim3 grid(NN / 128, NB * NHEAD);   // (16, 32)
        attn_mfma<<<grid, 256, 0, stream>>>(Qb, Kb, Vtb, AOb);
    }
    {
        dim3 grid(HIDDEN / 128, NB * NN / 128);   // (16, 32)
        gemm_bf16_nt<1><<<grid, 256, 0, stream>>>(
            AOb, Wob, nullptr, nullptr, nullptr, nullptr, nullptr, out,
            NB * NN, HIDDEN, HIDDEN);
    }
}

// Round 7
// 409.145 us; speedup vs baseline: 1.0750x; 1.0750x over previous
//
#include <hip/hip_runtime.h>
#include <math.h>

#define NB 2
#define NN 2048
#define HIDDEN 2048
#define NHEAD 16
#define DHEAD 128

typedef __attribute__((ext_vector_type(8))) short bf16x8;
typedef __attribute__((ext_vector_type(4))) float floatx4;

static __device__ __forceinline__ short f2bf(float f) {
    union { float f; unsigned u; } v; v.f = f;
    unsigned r = v.u + 0x7fffu + ((v.u >> 16) & 1u);
    return (short)(r >> 16);
}
static __device__ __forceinline__ void gload_lds16(const short* g, short* l) {
    __builtin_amdgcn_global_load_lds(
        (const __attribute__((address_space(1))) void*)g,
        (__attribute__((address_space(3))) void*)l, 16, 0, 0);
}

// ---------------------------------------------------------------------------
// cast 3 fp32 arrays to bf16
// ---------------------------------------------------------------------------
__global__ __launch_bounds__(256) void cast_bf16_3(
    const float* __restrict__ a, const float* __restrict__ b, const float* __restrict__ c,
    short* __restrict__ oa, short* __restrict__ ob, short* __restrict__ oc,
    int n4a, int n4b, int n4c)
{
    int i = blockIdx.x * 256 + threadIdx.x;
    const float* s; short* d; int j;
    if (i < n4a) { s = a; d = oa; j = i; }
    else if (i < n4a + n4b) { s = b; d = ob; j = i - n4a; }
    else if (i < n4a + n4b + n4c) { s = c; d = oc; j = i - n4a - n4b; }
    else return;
    float4 v = ((const float4*)s)[j];
    short4 o;
    o.x = f2bf(v.x); o.y = f2bf(v.y); o.z = f2bf(v.z); o.w = f2bf(v.w);
    ((short4*)d)[j] = o;
}

// ---------------------------------------------------------------------------
// QKV GEMM (round-5 verbatim — best measured 141 us): 256x128 tile / BK=64 /
// 8 waves, 2-phase counted-vmcnt pipeline.  Grid (48,16) = 768 = 3 exact
// rounds on 256 CUs.  BN=128 = one head per block.
// ---------------------------------------------------------------------------
__global__ __launch_bounds__(512, 2) void gemm_qkv_256x128(
    const short* __restrict__ A, const short* __restrict__ Bw,
    const float* __restrict__ cosT, const float* __restrict__ sinT,
    short* __restrict__ Qp, short* __restrict__ Kp, short* __restrict__ Vtp)
{
    __shared__ __align__(16) short AB[49152];   // 96 KB

    const int tid = threadIdx.x;
    const int w = tid >> 6;
    const int l = tid & 63;
    const int quad = l >> 4;
    const int l15 = l & 15;
    const int bn = blockIdx.x * 128;
    const int bm = blockIdx.y * 256;
    const int K = HIDDEN;

    // ---- staging sources/dests: 6 loads = A0(2) A1(2) B0(1) B1(1)
    const short* src[6];
    int ldst[6];
#pragma unroll
    for (int ld = 0; ld < 2; ++ld) {
        int chunk = ld * 512 + tid;          // 0..1023 (16B chunks)
        int row = chunk >> 3;                // 0..127
        int j = (chunk & 7) ^ (row & 7);     // inverse swizzle on global src
        int coff = j * 8;
        src[ld]     = A + (size_t)(bm + row) * K + coff;           // A0
        src[2 + ld] = A + (size_t)(bm + 128 + row) * K + coff;     // A1
        ldst[ld]     = chunk * 16;
        ldst[2 + ld] = 16384 + chunk * 16;
    }
    {
        int row = tid >> 3;                  // 0..63
        int j = (tid & 7) ^ (row & 7);
        int coff = j * 8;
        src[4] = Bw + (size_t)(bn + row) * K + coff;               // B0
        src[5] = Bw + (size_t)(bn + 64 + row) * K + coff;          // B1
        ldst[4] = 32768 + tid * 16;
        ldst[5] = 32768 + 8192 + tid * 16;
    }

    // ---- frag-read invariants (frag row&7 == l15&7 everywhere)
    const int xj = l15 & 7;
    const int jq0 = ((0 * 4 + quad) ^ xj) * 16;   // kc=0 chunk byte off
    const int jq1 = ((1 * 4 + quad) ^ xj) * 16;   // kc=1
    const int arow = (w * 32 + l15) * 128;        // + m*2048
    const int brow = 32768 + l15 * 128;           // + n*2048

    floatx4 acc[2][8];
#pragma unroll
    for (int i = 0; i < 2; ++i)
#pragma unroll
        for (int j = 0; j < 8; ++j) acc[i][j] = (floatx4){0.f, 0.f, 0.f, 0.f};

    // ---- prologue: stage tile 0 (A0,A1,B0,B1)
#pragma unroll
    for (int i = 0; i < 6; ++i)
        gload_lds16(src[i], (short*)((char*)AB + ldst[i]));

#define STAGE(i) gload_lds16(src[i] + kpf, (short*)((char*)AB + ldst[i] + so))
#define MFMA(d, x, y) d = __builtin_amdgcn_mfma_f32_16x16x32_bf16(x, y, d, 0, 0, 0)

    const int NT = K / 64;   // 32
#pragma unroll 1
    for (int t = 0; t < NT; ++t) {
        const int co = (t & 1) * 49152;     // compute buffer
        const int so = co ^ 49152;          // stage buffer
        int kpf = (t + 1) * 64;
        if (kpf == K) kpf = 0;              // wrap: dummy prefetch (drained below)

        bf16x8 a[2][2], b[4][2];

        // ---------------- P0: A(m0-1) x B(n0-3)
        asm volatile("s_waitcnt vmcnt(1)" ::: "memory");   // A0,A1,B0(t) valid
        __builtin_amdgcn_s_barrier();
#pragma unroll
        for (int m = 0; m < 2; ++m) {
            a[m][0] = *(const bf16x8*)((const char*)AB + co + arow + m * 2048 + jq0);
            a[m][1] = *(const bf16x8*)((const char*)AB + co + arow + m * 2048 + jq1);
        }
#pragma unroll
        for (int n = 0; n < 4; ++n) {
            b[n][0] = *(const bf16x8*)((const char*)AB + co + brow + n * 2048 + jq0);
            b[n][1] = *(const bf16x8*)((const char*)AB + co + brow + n * 2048 + jq1);
        }
        STAGE(0); STAGE(1); STAGE(2); STAGE(3); STAGE(4);
        __builtin_amdgcn_s_setprio(1);
#pragma unroll
        for (int m = 0; m < 2; ++m)
#pragma unroll
            for (int n = 0; n < 4; ++n) {
                MFMA(acc[m][n], a[m][0], b[n][0]);
                MFMA(acc[m][n], a[m][1], b[n][1]);
            }
        __builtin_amdgcn_s_setprio(0);

        // ---------------- P1: A(m0-1) x B(n4-7)
        asm volatile("s_waitcnt vmcnt(5)" ::: "memory");   // B1(t) valid
        __builtin_amdgcn_s_barrier();
#pragma unroll
        for (int n = 0; n < 4; ++n) {
            b[n][0] = *(const bf16x8*)((const char*)AB + co + brow + (4 + n) * 2048 + jq0);
            b[n][1] = *(const bf16x8*)((const char*)AB + co + brow + (4 + n) * 2048 + jq1);
        }
        STAGE(5);
        __builtin_amdgcn_s_setprio(1);
#pragma unroll
        for (int m = 0; m < 2; ++m)
#pragma unroll
            for (int n = 0; n < 4; ++n) {
                MFMA(acc[m][4 + n], a[m][0], b[n][0]);
                MFMA(acc[m][4 + n], a[m][1], b[n][1]);
            }
        __builtin_amdgcn_s_setprio(0);
    }
#undef STAGE
#undef MFMA

    // ---- drain wrap prefetches while LDS is still owned
    asm volatile("s_waitcnt vmcnt(0)" ::: "memory");

    // ---- epilogue: one head per block.  col(n) = n*16 + l15
    const int which = bn >> 11;                // 0=q 1=k 2=v
    const int head = (bn >> 7) & (NHEAD - 1);
    const float qsc = (which == 0) ? 0.12751791525f : 1.0f;  // 1/sqrt(128)*log2e

#pragma unroll
    for (int m = 0; m < 2; ++m) {
#pragma unroll
        for (int reg = 0; reg < 4; ++reg) {
            int gm = bm + w * 32 + m * 16 + quad * 4 + reg;
            int b2 = gm >> 11, nseq = gm & (NN - 1);
            int bh = b2 * NHEAD + head;
            if (which == 2) {
#pragma unroll
                for (int n = 0; n < 8; ++n) {
                    int d = n * 16 + l15;
                    Vtp[((size_t)bh * DHEAD + d) * NN + nseq] = f2bf(acc[m][n][reg]);
                }
            } else {
                short* dst = (which == 0 ? Qp : Kp) + ((size_t)bh * NN + nseq) * DHEAD;
#pragma unroll
                for (int p = 0; p < 4; ++p) {
                    int d0 = p * 16 + l15;     // < 64
                    float c = cosT[(size_t)nseq * DHEAD + d0];
                    float s = sinT[(size_t)nseq * DHEAD + d0];
                    float e0 = acc[m][p][reg];
                    float e1 = acc[m][p + 4][reg];
                    dst[d0]      = f2bf((e0 * c - e1 * s) * qsc);
                    dst[d0 + 64] = f2bf((e1 * c + e0 * s) * qsc);
                }
            }
        }
    }
}

// ---------------------------------------------------------------------------
// bf16 MFMA NT GEMM (kept for the output projection, MODE 1).
// ---------------------------------------------------------------------------
template <int MODE>
__global__ __launch_bounds__(256) void gemm_bf16_nt(
    const short* __restrict__ A, const short* __restrict__ Bw,
    const float* __restrict__ cosT, const float* __restrict__ sinT,
    short* __restrict__ Qp, short* __restrict__ Kp, short* __restrict__ Vtp,
    float* __restrict__ Cp, int M, int N, int K)
{
    __shared__ __align__(16) short AB[1280 * 8];   // 20.5 KB

    const int tid = threadIdx.x;
    const int w = tid >> 6;
    const int l = tid & 63;
    const int quad = l >> 4;
    const int l15 = l & 15;
    const int bm = blockIdx.y * 128;
    const int bn = blockIdx.x * 128;

    const int wm = (w & 1) * 64;
    const int wn2 = w >> 1;

    const short* gptr[5];
    short* lptr[5];
#pragma unroll
    for (int r5 = 0; r5 < 5; ++r5) {
        int s = r5 * 256 + tid;
        int m = (s < 640) ? s : s - 640;
        int row = m / 5;
        int ch = m - row * 5;
        if (ch == 4) ch = 0;
        gptr[r5] = ((s < 640) ? (A + (size_t)(bm + row) * K)
                              : (Bw + (size_t)(bn + row) * K)) + ch * 8;
        lptr[r5] = &AB[s * 8];
    }

    floatx4 acc[4][4];
#pragma unroll
    for (int i = 0; i < 4; ++i)
#pragma unroll
        for (int j = 0; j < 4; ++j) acc[i][j] = (floatx4){0.f, 0.f, 0.f, 0.f};

    for (int k0 = 0; k0 < K; k0 += 32) {
        __syncthreads();
#pragma unroll
        for (int r5 = 0; r5 < 5; ++r5)
            gload_lds16(gptr[r5] + k0, lptr[r5]);
        __syncthreads();

        bf16x8 af[4], bf[4];
#pragma unroll
        for (int i = 0; i < 4; ++i)
            af[i] = *(const bf16x8*)&AB[((wm + i * 16 + l15) * 5 + quad) * 8];
#pragma unroll
        for (int j = 0; j < 4; ++j) {
            int col = wn2 * 32 + (j & 1) * 16 + ((j >> 1) << 6);
            bf[j] = *(const bf16x8*)&AB[(640 + (col + l15) * 5 + quad) * 8];
        }
#pragma unroll
        for (int i = 0; i < 4; ++i)
#pragma unroll
            for (int j = 0; j < 4; ++j)
                acc[i][j] = __builtin_amdgcn_mfma_f32_16x16x32_bf16(af[i], bf[j], acc[i][j], 0, 0, 0);
    }

    if (MODE == 1) {
#pragma unroll
        for (int i = 0; i < 4; ++i) {
#pragma unroll
            for (int reg = 0; reg < 4; ++reg) {
                int row = bm + wm + i * 16 + quad * 4 + reg;
                float* crow = Cp + (size_t)row * N + bn;
#pragma unroll
                for (int j = 0; j < 4; ++j)
                    crow[wn2 * 32 + (j & 1) * 16 + ((j >> 1) << 6) + l15] = acc[i][j][reg];
            }
        }
    } else {
        const int which = bn >> 11;
        const int head = (bn >> 7) & (NHEAD - 1);
        const float qsc = (which == 0) ? 0.12751791525f : 1.0f;
#pragma unroll
        for (int i = 0; i < 4; ++i) {
#pragma unroll
            for (int reg = 0; reg < 4; ++reg) {
                int m = bm + wm + i * 16 + quad * 4 + reg;
                int b = m >> 11, n = m & (NN - 1);
                int bh = b * NHEAD + head;
                if (which == 2) {
#pragma unroll
                    for (int j = 0; j < 4; ++j) {
                        int d = wn2 * 32 + (j & 1) * 16 + ((j >> 1) << 6) + l15;
                        Vtp[((size_t)bh * DHEAD + d) * NN + n] = f2bf(acc[i][j][reg]);
                    }
                } else {
                    short* dst = (which == 0 ? Qp : Kp) + ((size_t)bh * NN + n) * DHEAD;
#pragma unroll
                    for (int j = 0; j < 2; ++j) {
                        int d0 = wn2 * 32 + j * 16 + l15;
                        float c = cosT[(size_t)n * DHEAD + d0];
                        float s = sinT[(size_t)n * DHEAD + d0];
                        float e0 = acc[i][j][reg], e1 = acc[i][j + 2][reg];
                        dst[d0]      = f2bf((e0 * c - e1 * s) * qsc);
                        dst[d0 + 64] = f2bf((e1 * c + e0 * s) * qsc);
                    }
                }
            }
        }
    }
}

// ---------------------------------------------------------------------------
// MFMA flash attention R7: 8 waves x 32 Q-rows = 256 Q-rows/block, grid
// (8,32) = 256 blocks = exactly 1/CU.  K/V DOUBLE-BUFFERED with counted
// drain: per kt, issue next tile's 4 LDS-DMAs, compute current tile from
// LDS, then vmcnt(0)+barrier (DMA latency hides under the ~full compute
// phase instead of being serially exposed as with __syncthreads draining).
// Fragment layouts / swizzles / no-max exp2 softmax verbatim from R6 attn.
// LDS: Ks 2x16KB + Vs 2x16KB + Ps[8][32][72] 36.9KB = 100.9 KB -> 1 blk/CU,
// 8 waves = 2/SIMD (same TLP as before, half the staging work per wave).
// Hazards: stage targets buf[nxt] while reading buf[cur] (disjoint); end
// barrier (a) globalizes per-thread vmcnt(0), (b) all reads of cur complete
// pre-barrier (lgkmcnt before MFMA use) -> next iter may DMA into cur.
// Last iteration stages nothing -> nothing outstanding at endpgm.
// ---------------------------------------------------------------------------
__global__ __launch_bounds__(512, 2) void attn_mfma8(
    const short* __restrict__ Qb, const short* __restrict__ Kb,
    const short* __restrict__ Vt, short* __restrict__ AOb)
{
    __shared__ __align__(16) short Ks[2][64 * 128];   // 32 KB, swz (s&15)^(row&15)
    __shared__ __align__(16) short Vs[2][128 * 64];   // 32 KB, swz (s&7)^(row&7)
    __shared__ __align__(16) short Ps[8][32][72];     // 36.9 KB bf16

    const int tid = threadIdx.x;       // 0..511
    const int w = tid >> 6;            // 0..7
    const int l = tid & 63;
    const int quad = l >> 4;
    const int l15 = l & 15;
    const int bh = blockIdx.y;
    const int qt = blockIdx.x * 256;

    const short* Qg = Qb + (size_t)bh * NN * DHEAD;
    const short* Kg = Kb + (size_t)bh * NN * DHEAD;
    const short* Vg = Vt + (size_t)bh * DHEAD * NN;

    // ---- Q fragments (registers, whole kernel)
    bf16x8 qf[2][4];
#pragma unroll
    for (int mi = 0; mi < 2; ++mi) {
        const short* qrow = Qg + (size_t)(qt + w * 32 + mi * 16 + l15) * DHEAD + quad * 8;
#pragma unroll
        for (int kc = 0; kc < 4; ++kc) qf[mi][kc] = *(const bf16x8*)(qrow + kc * 32);
    }

    // ---- staging addresses: 2 K-slots + 2 V-slots per thread (1024 slots ea.)
    const short* ksrc[2]; int kdst[2];
    const short* vsrc[2]; int vdst[2];
#pragma unroll
    for (int rr = 0; rr < 2; ++rr) {
        int s = rr * 512 + tid;
        {
            int row = s >> 4;                      // 0..63
            int j = (s & 15) ^ (row & 15);
            ksrc[rr] = Kg + (size_t)row * DHEAD + j * 8;   // + kt*DHEAD per tile
            kdst[rr] = s * 8;
        }
        {
            int row = s >> 3;                      // 0..127
            int c = (s & 7) ^ (row & 7);
            vsrc[rr] = Vg + (size_t)row * NN + c * 8;      // + kt per tile
            vdst[rr] = s * 8;
        }
    }

    floatx4 of[2][8];
#pragma unroll
    for (int mi = 0; mi < 2; ++mi)
#pragma unroll
        for (int dc = 0; dc < 8; ++dc) of[mi][dc] = (floatx4){0.f, 0.f, 0.f, 0.f};
    float ls[2][4] = {{0.f, 0.f, 0.f, 0.f}, {0.f, 0.f, 0.f, 0.f}};

    // ---- prologue: stage tile 0 into buf 0, globalize
#pragma unroll
    for (int rr = 0; rr < 2; ++rr) {
        gload_lds16(ksrc[rr], &Ks[0][0] + kdst[rr]);
        gload_lds16(vsrc[rr], &Vs[0][0] + vdst[rr]);
    }
    asm volatile("s_waitcnt vmcnt(0)" ::: "memory");
    __builtin_amdgcn_s_barrier();

    int cur = 0;
#pragma unroll 1
    for (int kt = 0; kt < NN; kt += 64) {
        // ---- issue next tile's staging into buf[cur^1]
        if (kt + 64 < NN) {
            const int nxt = cur ^ 1;
#pragma unroll
            for (int rr = 0; rr < 2; ++rr) {
                gload_lds16(ksrc[rr] + (size_t)(kt + 64) * DHEAD, &Ks[nxt][0] + kdst[rr]);
                gload_lds16(vsrc[rr] + (kt + 64), &Vs[nxt][0] + vdst[rr]);
            }
        }
        const short* kb = &Ks[cur][0];
        const short* vb = &Vs[cur][0];

        // ---- S = Q @ K^T: K-frags read once, used by both mi sub-tiles
        floatx4 sf[2][4];
#pragma unroll
        for (int n16 = 0; n16 < 4; ++n16) {
            bf16x8 kf[4];
            const short* kbase = kb + (n16 * 16 + l15) * 128;
#pragma unroll
            for (int kc = 0; kc < 4; ++kc)
                kf[kc] = *(const bf16x8*)&kbase[((4 * kc + quad) ^ l15) * 8];
#pragma unroll
            for (int mi = 0; mi < 2; ++mi) {
                floatx4 acc = (floatx4){0.f, 0.f, 0.f, 0.f};
#pragma unroll
                for (int kc = 0; kc < 4; ++kc)
                    acc = __builtin_amdgcn_mfma_f32_16x16x32_bf16(qf[mi][kc], kf[kc], acc, 0, 0, 0);
                sf[mi][n16] = acc;
            }
        }

        // ---- p = exp2(s); accumulate l per-lane; Ps bf16
#pragma unroll
        for (int mi = 0; mi < 2; ++mi)
#pragma unroll
            for (int n16 = 0; n16 < 4; ++n16)
#pragma unroll
                for (int r = 0; r < 4; ++r) {
                    float p = exp2f(sf[mi][n16][r]);
                    ls[mi][r] += p;
                    Ps[w][mi * 16 + quad * 4 + r][n16 * 16 + l15] = f2bf(p);
                }

        // ---- P: C-layout -> A-frags (same-wave LDS roundtrip)
        bf16x8 pa[2][2];
#pragma unroll
        for (int mi = 0; mi < 2; ++mi)
#pragma unroll
            for (int kc = 0; kc < 2; ++kc)
                pa[mi][kc] = *(const bf16x8*)&Ps[w][mi * 16 + l15][kc * 32 + quad * 8];

        // ---- O += P @ V: V-frags read once, used by both mi
#pragma unroll
        for (int dc = 0; dc < 8; ++dc) {
            int row = dc * 16 + l15;
#pragma unroll
            for (int kc = 0; kc < 2; ++kc) {
                bf16x8 vf = *(const bf16x8*)&vb[row * 64 + (((kc * 4 + quad) ^ (row & 7)) * 8)];
#pragma unroll
                for (int mi = 0; mi < 2; ++mi)
                    of[mi][dc] = __builtin_amdgcn_mfma_f32_16x16x32_bf16(
                                     pa[mi][kc], vf, of[mi][dc], 0, 0, 0);
            }
        }

        // ---- drain next-tile DMA (had the whole compute phase to land)
        asm volatile("s_waitcnt vmcnt(0)" ::: "memory");
        __builtin_amdgcn_s_barrier();
        cur ^= 1;
    }

    const int b = bh >> 4, h = bh & (NHEAD - 1);
#pragma unroll
    for (int mi = 0; mi < 2; ++mi)
#pragma unroll
        for (int r = 0; r < 4; ++r) {
            float s = ls[mi][r];
            s += __shfl_xor(s, 1, 64);
            s += __shfl_xor(s, 2, 64);
            s += __shfl_xor(s, 4, 64);
            s += __shfl_xor(s, 8, 64);
            float inv = 1.0f / s;
            int row = qt + w * 32 + mi * 16 + quad * 4 + r;
            short* dst = AOb + ((size_t)(b * NN + row)) * HIDDEN + h * DHEAD;
#pragma unroll
            for (int dc = 0; dc < 8; ++dc)
                dst[dc * 16 + l15] = f2bf(of[mi][dc][r] * inv);
        }
}

// ---------------------------------------------------------------------------
extern "C" void kernel_launch(void* const* d_in, const int* in_sizes, int n_in,
                              void* d_out, int out_size, void* d_ws, size_t ws_size,
                              hipStream_t stream)
{
    const float* hs = (const float*)d_in[0];
    const float* cosT = (const float*)d_in[1];
    const float* sinT = (const float*)d_in[2];
    const float* wqkv = (const float*)d_in[3];
    const float* wo = (const float*)d_in[4];
    float* out = (float*)d_out;

    const size_t N_HS = (size_t)NB * NN * HIDDEN;
    const size_t N_WQ = (size_t)3 * HIDDEN * HIDDEN;
    const size_t N_WO = (size_t)HIDDEN * HIDDEN;
    const size_t SZ = (size_t)NB * NHEAD * NN * DHEAD;

    short* Ahs   = (short*)d_ws;
    short* Wqkvb = Ahs + N_HS;
    short* Wob   = Wqkvb + N_WQ;
    short* Qb    = Wob + N_WO;
    short* Kb    = Qb + SZ;
    short* Vtb   = Kb + SZ;
    short* AOb   = Vtb + SZ;

    {
        int n4a = (int)(N_HS / 4), n4b = (int)(N_WQ / 4), n4c = (int)(N_WO / 4);
        int total = n4a + n4b + n4c;
        cast_bf16_3<<<(total + 255) / 256, 256, 0, stream>>>(
            hs, wqkv, wo, Ahs, Wqkvb, Wob, n4a, n4b, n4c);
    }
    {
        dim3 grid(3 * HIDDEN / 128, NB * NN / 256);   // (48, 16) = 768 = 3x256
        gemm_qkv_256x128<<<grid, 512, 0, stream>>>(
            Ahs, Wqkvb, cosT, sinT, Qb, Kb, Vtb);
    }
    {
        dim3 grid(NN / 256, NB * NHEAD);   // (8, 32) = 256 blocks = 1/CU
        attn_mfma8<<<grid, 512, 0, stream>>>(Qb, Kb, Vtb, AOb);
    }
    {
        dim3 grid(HIDDEN / 128, NB * NN / 128);   // (16, 32)
        gemm_bf16_nt<1><<<grid, 256, 0, stream>>>(
            AOb, Wob, nullptr, nullptr, nullptr, nullptr, nullptr, out,
            NB * NN, HIDDEN, HIDDEN);
    }
}

// Round 8
// 400.485 us; speedup vs baseline: 1.0983x; 1.0216x over previous
//
#include <hip/hip_runtime.h>
#include <math.h>

#define NB 2
#define NN 2048
#define HIDDEN 2048
#define NHEAD 16
#define DHEAD 128

typedef __attribute__((ext_vector_type(8))) short bf16x8;
typedef __attribute__((ext_vector_type(4))) float floatx4;

static __device__ __forceinline__ short f2bf(float f) {
    union { float f; unsigned u; } v; v.f = f;
    unsigned r = v.u + 0x7fffu + ((v.u >> 16) & 1u);
    return (short)(r >> 16);
}
static __device__ __forceinline__ void gload_lds16(const short* g, short* l) {
    __builtin_amdgcn_global_load_lds(
        (const __attribute__((address_space(1))) void*)g,
        (__attribute__((address_space(3))) void*)l, 16, 0, 0);
}

// ---------------------------------------------------------------------------
// cast 3 fp32 arrays to bf16
// ---------------------------------------------------------------------------
__global__ __launch_bounds__(256) void cast_bf16_3(
    const float* __restrict__ a, const float* __restrict__ b, const float* __restrict__ c,
    short* __restrict__ oa, short* __restrict__ ob, short* __restrict__ oc,
    int n4a, int n4b, int n4c)
{
    int i = blockIdx.x * 256 + threadIdx.x;
    const float* s; short* d; int j;
    if (i < n4a) { s = a; d = oa; j = i; }
    else if (i < n4a + n4b) { s = b; d = ob; j = i - n4a; }
    else if (i < n4a + n4b + n4c) { s = c; d = oc; j = i - n4a - n4b; }
    else return;
    float4 v = ((const float4*)s)[j];
    short4 o;
    o.x = f2bf(v.x); o.y = f2bf(v.y); o.z = f2bf(v.z); o.w = f2bf(v.w);
    ((short4*)d)[j] = o;
}

// ---------------------------------------------------------------------------
// QKV GEMM (round-5 verbatim — best measured 141 us): 256x128 tile / BK=64 /
// 8 waves, 2-phase counted-vmcnt pipeline.  Grid (48,16) = 768 = 3 exact
// rounds on 256 CUs.  BN=128 = one head per block.
// ---------------------------------------------------------------------------
__global__ __launch_bounds__(512, 2) void gemm_qkv_256x128(
    const short* __restrict__ A, const short* __restrict__ Bw,
    const float* __restrict__ cosT, const float* __restrict__ sinT,
    short* __restrict__ Qp, short* __restrict__ Kp, short* __restrict__ Vtp)
{
    __shared__ __align__(16) short AB[49152];   // 96 KB

    const int tid = threadIdx.x;
    const int w = tid >> 6;
    const int l = tid & 63;
    const int quad = l >> 4;
    const int l15 = l & 15;
    const int bn = blockIdx.x * 128;
    const int bm = blockIdx.y * 256;
    const int K = HIDDEN;

    // ---- staging sources/dests: 6 loads = A0(2) A1(2) B0(1) B1(1)
    const short* src[6];
    int ldst[6];
#pragma unroll
    for (int ld = 0; ld < 2; ++ld) {
        int chunk = ld * 512 + tid;          // 0..1023 (16B chunks)
        int row = chunk >> 3;                // 0..127
        int j = (chunk & 7) ^ (row & 7);     // inverse swizzle on global src
        int coff = j * 8;
        src[ld]     = A + (size_t)(bm + row) * K + coff;           // A0
        src[2 + ld] = A + (size_t)(bm + 128 + row) * K + coff;     // A1
        ldst[ld]     = chunk * 16;
        ldst[2 + ld] = 16384 + chunk * 16;
    }
    {
        int row = tid >> 3;                  // 0..63
        int j = (tid & 7) ^ (row & 7);
        int coff = j * 8;
        src[4] = Bw + (size_t)(bn + row) * K + coff;               // B0
        src[5] = Bw + (size_t)(bn + 64 + row) * K + coff;          // B1
        ldst[4] = 32768 + tid * 16;
        ldst[5] = 32768 + 8192 + tid * 16;
    }

    // ---- frag-read invariants (frag row&7 == l15&7 everywhere)
    const int xj = l15 & 7;
    const int jq0 = ((0 * 4 + quad) ^ xj) * 16;   // kc=0 chunk byte off
    const int jq1 = ((1 * 4 + quad) ^ xj) * 16;   // kc=1
    const int arow = (w * 32 + l15) * 128;        // + m*2048
    const int brow = 32768 + l15 * 128;           // + n*2048

    floatx4 acc[2][8];
#pragma unroll
    for (int i = 0; i < 2; ++i)
#pragma unroll
        for (int j = 0; j < 8; ++j) acc[i][j] = (floatx4){0.f, 0.f, 0.f, 0.f};

    // ---- prologue: stage tile 0 (A0,A1,B0,B1)
#pragma unroll
    for (int i = 0; i < 6; ++i)
        gload_lds16(src[i], (short*)((char*)AB + ldst[i]));

#define STAGE(i) gload_lds16(src[i] + kpf, (short*)((char*)AB + ldst[i] + so))
#define MFMA(d, x, y) d = __builtin_amdgcn_mfma_f32_16x16x32_bf16(x, y, d, 0, 0, 0)

    const int NT = K / 64;   // 32
#pragma unroll 1
    for (int t = 0; t < NT; ++t) {
        const int co = (t & 1) * 49152;     // compute buffer
        const int so = co ^ 49152;          // stage buffer
        int kpf = (t + 1) * 64;
        if (kpf == K) kpf = 0;              // wrap: dummy prefetch (drained below)

        bf16x8 a[2][2], b[4][2];

        // ---------------- P0: A(m0-1) x B(n0-3)
        asm volatile("s_waitcnt vmcnt(1)" ::: "memory");   // A0,A1,B0(t) valid
        __builtin_amdgcn_s_barrier();
#pragma unroll
        for (int m = 0; m < 2; ++m) {
            a[m][0] = *(const bf16x8*)((const char*)AB + co + arow + m * 2048 + jq0);
            a[m][1] = *(const bf16x8*)((const char*)AB + co + arow + m * 2048 + jq1);
        }
#pragma unroll
        for (int n = 0; n < 4; ++n) {
            b[n][0] = *(const bf16x8*)((const char*)AB + co + brow + n * 2048 + jq0);
            b[n][1] = *(const bf16x8*)((const char*)AB + co + brow + n * 2048 + jq1);
        }
        STAGE(0); STAGE(1); STAGE(2); STAGE(3); STAGE(4);
        __builtin_amdgcn_s_setprio(1);
#pragma unroll
        for (int m = 0; m < 2; ++m)
#pragma unroll
            for (int n = 0; n < 4; ++n) {
                MFMA(acc[m][n], a[m][0], b[n][0]);
                MFMA(acc[m][n], a[m][1], b[n][1]);
            }
        __builtin_amdgcn_s_setprio(0);

        // ---------------- P1: A(m0-1) x B(n4-7)
        asm volatile("s_waitcnt vmcnt(5)" ::: "memory");   // B1(t) valid
        __builtin_amdgcn_s_barrier();
#pragma unroll
        for (int n = 0; n < 4; ++n) {
            b[n][0] = *(const bf16x8*)((const char*)AB + co + brow + (4 + n) * 2048 + jq0);
            b[n][1] = *(const bf16x8*)((const char*)AB + co + brow + (4 + n) * 2048 + jq1);
        }
        STAGE(5);
        __builtin_amdgcn_s_setprio(1);
#pragma unroll
        for (int m = 0; m < 2; ++m)
#pragma unroll
            for (int n = 0; n < 4; ++n) {
                MFMA(acc[m][4 + n], a[m][0], b[n][0]);
                MFMA(acc[m][4 + n], a[m][1], b[n][1]);
            }
        __builtin_amdgcn_s_setprio(0);
    }
#undef STAGE
#undef MFMA

    // ---- drain wrap prefetches while LDS is still owned
    asm volatile("s_waitcnt vmcnt(0)" ::: "memory");

    // ---- epilogue: one head per block.  col(n) = n*16 + l15
    const int which = bn >> 11;                // 0=q 1=k 2=v
    const int head = (bn >> 7) & (NHEAD - 1);
    const float qsc = (which == 0) ? 0.12751791525f : 1.0f;  // 1/sqrt(128)*log2e

#pragma unroll
    for (int m = 0; m < 2; ++m) {
#pragma unroll
        for (int reg = 0; reg < 4; ++reg) {
            int gm = bm + w * 32 + m * 16 + quad * 4 + reg;
            int b2 = gm >> 11, nseq = gm & (NN - 1);
            int bh = b2 * NHEAD + head;
            if (which == 2) {
#pragma unroll
                for (int n = 0; n < 8; ++n) {
                    int d = n * 16 + l15;
                    Vtp[((size_t)bh * DHEAD + d) * NN + nseq] = f2bf(acc[m][n][reg]);
                }
            } else {
                short* dst = (which == 0 ? Qp : Kp) + ((size_t)bh * NN + nseq) * DHEAD;
#pragma unroll
                for (int p = 0; p < 4; ++p) {
                    int d0 = p * 16 + l15;     // < 64
                    float c = cosT[(size_t)nseq * DHEAD + d0];
                    float s = sinT[(size_t)nseq * DHEAD + d0];
                    float e0 = acc[m][p][reg];
                    float e1 = acc[m][p + 4][reg];
                    dst[d0]      = f2bf((e0 * c - e1 * s) * qsc);
                    dst[d0 + 64] = f2bf((e1 * c + e0 * s) * qsc);
                }
            }
        }
    }
}

// ---------------------------------------------------------------------------
// Output projection GEMM: same 256x128 / BK=64 / 8-wave 2-phase pipeline as
// gemm_qkv_256x128, fp32 C epilogue.  Grid (16,16) = 256 blocks = exactly
// 1/CU (zero tail).  A = AOb bf16 [4096][2048], B = Wob bf16 [2048][2048]
// (NT), C fp32 [4096][2048].
// ---------------------------------------------------------------------------
__global__ __launch_bounds__(512, 2) void gemm_out_256x128(
    const short* __restrict__ A, const short* __restrict__ Bw,
    float* __restrict__ Cp)
{
    __shared__ __align__(16) short AB[49152];   // 96 KB

    const int tid = threadIdx.x;
    const int w = tid >> 6;
    const int l = tid & 63;
    const int quad = l >> 4;
    const int l15 = l & 15;
    const int bn = blockIdx.x * 128;
    const int bm = blockIdx.y * 256;
    const int K = HIDDEN;

    // ---- staging sources/dests: 6 loads = A0(2) A1(2) B0(1) B1(1)
    const short* src[6];
    int ldst[6];
#pragma unroll
    for (int ld = 0; ld < 2; ++ld) {
        int chunk = ld * 512 + tid;
        int row = chunk >> 3;
        int j = (chunk & 7) ^ (row & 7);
        int coff = j * 8;
        src[ld]     = A + (size_t)(bm + row) * K + coff;
        src[2 + ld] = A + (size_t)(bm + 128 + row) * K + coff;
        ldst[ld]     = chunk * 16;
        ldst[2 + ld] = 16384 + chunk * 16;
    }
    {
        int row = tid >> 3;
        int j = (tid & 7) ^ (row & 7);
        int coff = j * 8;
        src[4] = Bw + (size_t)(bn + row) * K + coff;
        src[5] = Bw + (size_t)(bn + 64 + row) * K + coff;
        ldst[4] = 32768 + tid * 16;
        ldst[5] = 32768 + 8192 + tid * 16;
    }

    const int xj = l15 & 7;
    const int jq0 = ((0 * 4 + quad) ^ xj) * 16;
    const int jq1 = ((1 * 4 + quad) ^ xj) * 16;
    const int arow = (w * 32 + l15) * 128;
    const int brow = 32768 + l15 * 128;

    floatx4 acc[2][8];
#pragma unroll
    for (int i = 0; i < 2; ++i)
#pragma unroll
        for (int j = 0; j < 8; ++j) acc[i][j] = (floatx4){0.f, 0.f, 0.f, 0.f};

#pragma unroll
    for (int i = 0; i < 6; ++i)
        gload_lds16(src[i], (short*)((char*)AB + ldst[i]));

#define STAGE(i) gload_lds16(src[i] + kpf, (short*)((char*)AB + ldst[i] + so))
#define MFMA(d, x, y) d = __builtin_amdgcn_mfma_f32_16x16x32_bf16(x, y, d, 0, 0, 0)

    const int NT = K / 64;   // 32
#pragma unroll 1
    for (int t = 0; t < NT; ++t) {
        const int co = (t & 1) * 49152;
        const int so = co ^ 49152;
        int kpf = (t + 1) * 64;
        if (kpf == K) kpf = 0;

        bf16x8 a[2][2], b[4][2];

        // ---------------- P0
        asm volatile("s_waitcnt vmcnt(1)" ::: "memory");
        __builtin_amdgcn_s_barrier();
#pragma unroll
        for (int m = 0; m < 2; ++m) {
            a[m][0] = *(const bf16x8*)((const char*)AB + co + arow + m * 2048 + jq0);
            a[m][1] = *(const bf16x8*)((const char*)AB + co + arow + m * 2048 + jq1);
        }
#pragma unroll
        for (int n = 0; n < 4; ++n) {
            b[n][0] = *(const bf16x8*)((const char*)AB + co + brow + n * 2048 + jq0);
            b[n][1] = *(const bf16x8*)((const char*)AB + co + brow + n * 2048 + jq1);
        }
        STAGE(0); STAGE(1); STAGE(2); STAGE(3); STAGE(4);
        __builtin_amdgcn_s_setprio(1);
#pragma unroll
        for (int m = 0; m < 2; ++m)
#pragma unroll
            for (int n = 0; n < 4; ++n) {
                MFMA(acc[m][n], a[m][0], b[n][0]);
                MFMA(acc[m][n], a[m][1], b[n][1]);
            }
        __builtin_amdgcn_s_setprio(0);

        // ---------------- P1
        asm volatile("s_waitcnt vmcnt(5)" ::: "memory");
        __builtin_amdgcn_s_barrier();
#pragma unroll
        for (int n = 0; n < 4; ++n) {
            b[n][0] = *(const bf16x8*)((const char*)AB + co + brow + (4 + n) * 2048 + jq0);
            b[n][1] = *(const bf16x8*)((const char*)AB + co + brow + (4 + n) * 2048 + jq1);
        }
        STAGE(5);
        __builtin_amdgcn_s_setprio(1);
#pragma unroll
        for (int m = 0; m < 2; ++m)
#pragma unroll
            for (int n = 0; n < 4; ++n) {
                MFMA(acc[m][4 + n], a[m][0], b[n][0]);
                MFMA(acc[m][4 + n], a[m][1], b[n][1]);
            }
        __builtin_amdgcn_s_setprio(0);
    }
#undef STAGE
#undef MFMA

    asm volatile("s_waitcnt vmcnt(0)" ::: "memory");

    // ---- epilogue: plain fp32 store
#pragma unroll
    for (int m = 0; m < 2; ++m) {
#pragma unroll
        for (int reg = 0; reg < 4; ++reg) {
            int row = bm + w * 32 + m * 16 + quad * 4 + reg;
            float* crow = Cp + (size_t)row * HIDDEN + bn;
#pragma unroll
            for (int n = 0; n < 8; ++n)
                crow[n * 16 + l15] = acc[m][n][reg];
        }
    }
}

// ---------------------------------------------------------------------------
// MFMA flash attention R7: 8 waves x 32 Q-rows = 256 Q-rows/block, grid
// (8,32) = 256 blocks = exactly 1/CU.  K/V double-buffered, counted drain.
// ---------------------------------------------------------------------------
__global__ __launch_bounds__(512, 2) void attn_mfma8(
    const short* __restrict__ Qb, const short* __restrict__ Kb,
    const short* __restrict__ Vt, short* __restrict__ AOb)
{
    __shared__ __align__(16) short Ks[2][64 * 128];   // 32 KB, swz (s&15)^(row&15)
    __shared__ __align__(16) short Vs[2][128 * 64];   // 32 KB, swz (s&7)^(row&7)
    __shared__ __align__(16) short Ps[8][32][72];     // 36.9 KB bf16

    const int tid = threadIdx.x;       // 0..511
    const int w = tid >> 6;            // 0..7
    const int l = tid & 63;
    const int quad = l >> 4;
    const int l15 = l & 15;
    const int bh = blockIdx.y;
    const int qt = blockIdx.x * 256;

    const short* Qg = Qb + (size_t)bh * NN * DHEAD;
    const short* Kg = Kb + (size_t)bh * NN * DHEAD;
    const short* Vg = Vt + (size_t)bh * DHEAD * NN;

    // ---- Q fragments (registers, whole kernel)
    bf16x8 qf[2][4];
#pragma unroll
    for (int mi = 0; mi < 2; ++mi) {
        const short* qrow = Qg + (size_t)(qt + w * 32 + mi * 16 + l15) * DHEAD + quad * 8;
#pragma unroll
        for (int kc = 0; kc < 4; ++kc) qf[mi][kc] = *(const bf16x8*)(qrow + kc * 32);
    }

    // ---- staging addresses: 2 K-slots + 2 V-slots per thread
    const short* ksrc[2]; int kdst[2];
    const short* vsrc[2]; int vdst[2];
#pragma unroll
    for (int rr = 0; rr < 2; ++rr) {
        int s = rr * 512 + tid;
        {
            int row = s >> 4;
            int j = (s & 15) ^ (row & 15);
            ksrc[rr] = Kg + (size_t)row * DHEAD + j * 8;
            kdst[rr] = s * 8;
        }
        {
            int row = s >> 3;
            int c = (s & 7) ^ (row & 7);
            vsrc[rr] = Vg + (size_t)row * NN + c * 8;
            vdst[rr] = s * 8;
        }
    }

    floatx4 of[2][8];
#pragma unroll
    for (int mi = 0; mi < 2; ++mi)
#pragma unroll
        for (int dc = 0; dc < 8; ++dc) of[mi][dc] = (floatx4){0.f, 0.f, 0.f, 0.f};
    float ls[2][4] = {{0.f, 0.f, 0.f, 0.f}, {0.f, 0.f, 0.f, 0.f}};

    // ---- prologue: stage tile 0 into buf 0, globalize
#pragma unroll
    for (int rr = 0; rr < 2; ++rr) {
        gload_lds16(ksrc[rr], &Ks[0][0] + kdst[rr]);
        gload_lds16(vsrc[rr], &Vs[0][0] + vdst[rr]);
    }
    asm volatile("s_waitcnt vmcnt(0)" ::: "memory");
    __builtin_amdgcn_s_barrier();

    int cur = 0;
#pragma unroll 1
    for (int kt = 0; kt < NN; kt += 64) {
        // ---- issue next tile's staging into buf[cur^1]
        if (kt + 64 < NN) {
            const int nxt = cur ^ 1;
#pragma unroll
            for (int rr = 0; rr < 2; ++rr) {
                gload_lds16(ksrc[rr] + (size_t)(kt + 64) * DHEAD, &Ks[nxt][0] + kdst[rr]);
                gload_lds16(vsrc[rr] + (kt + 64), &Vs[nxt][0] + vdst[rr]);
            }
        }
        const short* kb = &Ks[cur][0];
        const short* vb = &Vs[cur][0];

        // ---- S = Q @ K^T
        floatx4 sf[2][4];
#pragma unroll
        for (int n16 = 0; n16 < 4; ++n16) {
            bf16x8 kf[4];
            const short* kbase = kb + (n16 * 16 + l15) * 128;
#pragma unroll
            for (int kc = 0; kc < 4; ++kc)
                kf[kc] = *(const bf16x8*)&kbase[((4 * kc + quad) ^ l15) * 8];
#pragma unroll
            for (int mi = 0; mi < 2; ++mi) {
                floatx4 acc = (floatx4){0.f, 0.f, 0.f, 0.f};
#pragma unroll
                for (int kc = 0; kc < 4; ++kc)
                    acc = __builtin_amdgcn_mfma_f32_16x16x32_bf16(qf[mi][kc], kf[kc], acc, 0, 0, 0);
                sf[mi][n16] = acc;
            }
        }

        // ---- p = exp2(s); accumulate l per-lane; Ps bf16
#pragma unroll
        for (int mi = 0; mi < 2; ++mi)
#pragma unroll
            for (int n16 = 0; n16 < 4; ++n16)
#pragma unroll
                for (int r = 0; r < 4; ++r) {
                    float p = exp2f(sf[mi][n16][r]);
                    ls[mi][r] += p;
                    Ps[w][mi * 16 + quad * 4 + r][n16 * 16 + l15] = f2bf(p);
                }

        // ---- P: C-layout -> A-frags
        bf16x8 pa[2][2];
#pragma unroll
        for (int mi = 0; mi < 2; ++mi)
#pragma unroll
            for (int kc = 0; kc < 2; ++kc)
                pa[mi][kc] = *(const bf16x8*)&Ps[w][mi * 16 + l15][kc * 32 + quad * 8];

        // ---- O += P @ V
#pragma unroll
        for (int dc = 0; dc < 8; ++dc) {
            int row = dc * 16 + l15;
#pragma unroll
            for (int kc = 0; kc < 2; ++kc) {
                bf16x8 vf = *(const bf16x8*)&vb[row * 64 + (((kc * 4 + quad) ^ (row & 7)) * 8)];
#pragma unroll
                for (int mi = 0; mi < 2; ++mi)
                    of[mi][dc] = __builtin_amdgcn_mfma_f32_16x16x32_bf16(
                                     pa[mi][kc], vf, of[mi][dc], 0, 0, 0);
            }
        }

        // ---- drain next-tile DMA
        asm volatile("s_waitcnt vmcnt(0)" ::: "memory");
        __builtin_amdgcn_s_barrier();
        cur ^= 1;
    }

    const int b = bh >> 4, h = bh & (NHEAD - 1);
#pragma unroll
    for (int mi = 0; mi < 2; ++mi)
#pragma unroll
        for (int r = 0; r < 4; ++r) {
            float s = ls[mi][r];
            s += __shfl_xor(s, 1, 64);
            s += __shfl_xor(s, 2, 64);
            s += __shfl_xor(s, 4, 64);
            s += __shfl_xor(s, 8, 64);
            float inv = 1.0f / s;
            int row = qt + w * 32 + mi * 16 + quad * 4 + r;
            short* dst = AOb + ((size_t)(b * NN + row)) * HIDDEN + h * DHEAD;
#pragma unroll
            for (int dc = 0; dc < 8; ++dc)
                dst[dc * 16 + l15] = f2bf(of[mi][dc][r] * inv);
        }
}

// ---------------------------------------------------------------------------
extern "C" void kernel_launch(void* const* d_in, const int* in_sizes, int n_in,
                              void* d_out, int out_size, void* d_ws, size_t ws_size,
                              hipStream_t stream)
{
    const float* hs = (const float*)d_in[0];
    const float* cosT = (const float*)d_in[1];
    const float* sinT = (const float*)d_in[2];
    const float* wqkv = (const float*)d_in[3];
    const float* wo = (const float*)d_in[4];
    float* out = (float*)d_out;

    const size_t N_HS = (size_t)NB * NN * HIDDEN;
    const size_t N_WQ = (size_t)3 * HIDDEN * HIDDEN;
    const size_t N_WO = (size_t)HIDDEN * HIDDEN;
    const size_t SZ = (size_t)NB * NHEAD * NN * DHEAD;

    short* Ahs   = (short*)d_ws;
    short* Wqkvb = Ahs + N_HS;
    short* Wob   = Wqkvb + N_WQ;
    short* Qb    = Wob + N_WO;
    short* Kb    = Qb + SZ;
    short* Vtb   = Kb + SZ;
    short* AOb   = Vtb + SZ;

    {
        int n4a = (int)(N_HS / 4), n4b = (int)(N_WQ / 4), n4c = (int)(N_WO / 4);
        int total = n4a + n4b + n4c;
        cast_bf16_3<<<(total + 255) / 256, 256, 0, stream>>>(
            hs, wqkv, wo, Ahs, Wqkvb, Wob, n4a, n4b, n4c);
    }
    {
        dim3 grid(3 * HIDDEN / 128, NB * NN / 256);   // (48, 16) = 768 = 3x256
        gemm_qkv_256x128<<<grid, 512, 0, stream>>>(
            Ahs, Wqkvb, cosT, sinT, Qb, Kb, Vtb);
    }
    {
        dim3 grid(NN / 256, NB * NHEAD);   // (8, 32) = 256 blocks = 1/CU
        attn_mfma8<<<grid, 512, 0, stream>>>(Qb, Kb, Vtb, AOb);
    }
    {
        dim3 grid(HIDDEN / 128, NB * NN / 256);   // (16, 16) = 256 = 1/CU
        gemm_out_256x128<<<grid, 512, 0, stream>>>(AOb, Wob, out);
    }
}

// Round 9
// 382.725 us; speedup vs baseline: 1.1492x; 1.0464x over previous
//
#include <hip/hip_runtime.h>
#include <math.h>

#define NB 2
#define NN 2048
#define HIDDEN 2048
#define NHEAD 16
#define DHEAD 128

typedef __attribute__((ext_vector_type(8))) short bf16x8;
typedef __attribute__((ext_vector_type(4))) float floatx4;

static __device__ __forceinline__ short f2bf(float f) {
    union { float f; unsigned u; } v; v.f = f;
    unsigned r = v.u + 0x7fffu + ((v.u >> 16) & 1u);
    return (short)(r >> 16);
}
static __device__ __forceinline__ void gload_lds16(const short* g, short* l) {
    __builtin_amdgcn_global_load_lds(
        (const __attribute__((address_space(1))) void*)g,
        (__attribute__((address_space(3))) void*)l, 16, 0, 0);
}

// ---------------------------------------------------------------------------
// cast 3 fp32 arrays to bf16
// ---------------------------------------------------------------------------
__global__ __launch_bounds__(256) void cast_bf16_3(
    const float* __restrict__ a, const float* __restrict__ b, const float* __restrict__ c,
    short* __restrict__ oa, short* __restrict__ ob, short* __restrict__ oc,
    int n4a, int n4b, int n4c)
{
    int i = blockIdx.x * 256 + threadIdx.x;
    const float* s; short* d; int j;
    if (i < n4a) { s = a; d = oa; j = i; }
    else if (i < n4a + n4b) { s = b; d = ob; j = i - n4a; }
    else if (i < n4a + n4b + n4c) { s = c; d = oc; j = i - n4a - n4b; }
    else return;
    float4 v = ((const float4*)s)[j];
    short4 o;
    o.x = f2bf(v.x); o.y = f2bf(v.y); o.z = f2bf(v.z); o.w = f2bf(v.w);
    ((short4*)d)[j] = o;
}

// ---------------------------------------------------------------------------
// QKV GEMM (round-5 verbatim — best measured 141 us): 256x128 tile / BK=64 /
// 8 waves, 2-phase counted-vmcnt pipeline.  Grid (48,16) = 768 = 3 exact
// rounds on 256 CUs.  BN=128 = one head per block.
// ---------------------------------------------------------------------------
__global__ __launch_bounds__(512, 2) void gemm_qkv_256x128(
    const short* __restrict__ A, const short* __restrict__ Bw,
    const float* __restrict__ cosT, const float* __restrict__ sinT,
    short* __restrict__ Qp, short* __restrict__ Kp, short* __restrict__ Vtp)
{
    __shared__ __align__(16) short AB[49152];   // 96 KB

    const int tid = threadIdx.x;
    const int w = tid >> 6;
    const int l = tid & 63;
    const int quad = l >> 4;
    const int l15 = l & 15;
    const int bn = blockIdx.x * 128;
    const int bm = blockIdx.y * 256;
    const int K = HIDDEN;

    // ---- staging sources/dests: 6 loads = A0(2) A1(2) B0(1) B1(1)
    const short* src[6];
    int ldst[6];
#pragma unroll
    for (int ld = 0; ld < 2; ++ld) {
        int chunk = ld * 512 + tid;          // 0..1023 (16B chunks)
        int row = chunk >> 3;                // 0..127
        int j = (chunk & 7) ^ (row & 7);     // inverse swizzle on global src
        int coff = j * 8;
        src[ld]     = A + (size_t)(bm + row) * K + coff;           // A0
        src[2 + ld] = A + (size_t)(bm + 128 + row) * K + coff;     // A1
        ldst[ld]     = chunk * 16;
        ldst[2 + ld] = 16384 + chunk * 16;
    }
    {
        int row = tid >> 3;                  // 0..63
        int j = (tid & 7) ^ (row & 7);
        int coff = j * 8;
        src[4] = Bw + (size_t)(bn + row) * K + coff;               // B0
        src[5] = Bw + (size_t)(bn + 64 + row) * K + coff;          // B1
        ldst[4] = 32768 + tid * 16;
        ldst[5] = 32768 + 8192 + tid * 16;
    }

    // ---- frag-read invariants (frag row&7 == l15&7 everywhere)
    const int xj = l15 & 7;
    const int jq0 = ((0 * 4 + quad) ^ xj) * 16;   // kc=0 chunk byte off
    const int jq1 = ((1 * 4 + quad) ^ xj) * 16;   // kc=1
    const int arow = (w * 32 + l15) * 128;        // + m*2048
    const int brow = 32768 + l15 * 128;           // + n*2048

    floatx4 acc[2][8];
#pragma unroll
    for (int i = 0; i < 2; ++i)
#pragma unroll
        for (int j = 0; j < 8; ++j) acc[i][j] = (floatx4){0.f, 0.f, 0.f, 0.f};

    // ---- prologue: stage tile 0 (A0,A1,B0,B1)
#pragma unroll
    for (int i = 0; i < 6; ++i)
        gload_lds16(src[i], (short*)((char*)AB + ldst[i]));

#define STAGE(i) gload_lds16(src[i] + kpf, (short*)((char*)AB + ldst[i] + so))
#define MFMA(d, x, y) d = __builtin_amdgcn_mfma_f32_16x16x32_bf16(x, y, d, 0, 0, 0)

    const int NT = K / 64;   // 32
#pragma unroll 1
    for (int t = 0; t < NT; ++t) {
        const int co = (t & 1) * 49152;     // compute buffer
        const int so = co ^ 49152;          // stage buffer
        int kpf = (t + 1) * 64;
        if (kpf == K) kpf = 0;              // wrap: dummy prefetch (drained below)

        bf16x8 a[2][2], b[4][2];

        // ---------------- P0: A(m0-1) x B(n0-3)
        asm volatile("s_waitcnt vmcnt(1)" ::: "memory");   // A0,A1,B0(t) valid
        __builtin_amdgcn_s_barrier();
#pragma unroll
        for (int m = 0; m < 2; ++m) {
            a[m][0] = *(const bf16x8*)((const char*)AB + co + arow + m * 2048 + jq0);
            a[m][1] = *(const bf16x8*)((const char*)AB + co + arow + m * 2048 + jq1);
        }
#pragma unroll
        for (int n = 0; n < 4; ++n) {
            b[n][0] = *(const bf16x8*)((const char*)AB + co + brow + n * 2048 + jq0);
            b[n][1] = *(const bf16x8*)((const char*)AB + co + brow + n * 2048 + jq1);
        }
        STAGE(0); STAGE(1); STAGE(2); STAGE(3); STAGE(4);
        __builtin_amdgcn_s_setprio(1);
#pragma unroll
        for (int m = 0; m < 2; ++m)
#pragma unroll
            for (int n = 0; n < 4; ++n) {
                MFMA(acc[m][n], a[m][0], b[n][0]);
                MFMA(acc[m][n], a[m][1], b[n][1]);
            }
        __builtin_amdgcn_s_setprio(0);

        // ---------------- P1: A(m0-1) x B(n4-7)
        asm volatile("s_waitcnt vmcnt(5)" ::: "memory");   // B1(t) valid
        __builtin_amdgcn_s_barrier();
#pragma unroll
        for (int n = 0; n < 4; ++n) {
            b[n][0] = *(const bf16x8*)((const char*)AB + co + brow + (4 + n) * 2048 + jq0);
            b[n][1] = *(const bf16x8*)((const char*)AB + co + brow + (4 + n) * 2048 + jq1);
        }
        STAGE(5);
        __builtin_amdgcn_s_setprio(1);
#pragma unroll
        for (int m = 0; m < 2; ++m)
#pragma unroll
            for (int n = 0; n < 4; ++n) {
                MFMA(acc[m][4 + n], a[m][0], b[n][0]);
                MFMA(acc[m][4 + n], a[m][1], b[n][1]);
            }
        __builtin_amdgcn_s_setprio(0);
    }
#undef STAGE
#undef MFMA

    // ---- drain wrap prefetches while LDS is still owned
    asm volatile("s_waitcnt vmcnt(0)" ::: "memory");

    // ---- epilogue: one head per block.  col(n) = n*16 + l15
    const int which = bn >> 11;                // 0=q 1=k 2=v
    const int head = (bn >> 7) & (NHEAD - 1);
    const float qsc = (which == 0) ? 0.12751791525f : 1.0f;  // 1/sqrt(128)*log2e

#pragma unroll
    for (int m = 0; m < 2; ++m) {
#pragma unroll
        for (int reg = 0; reg < 4; ++reg) {
            int gm = bm + w * 32 + m * 16 + quad * 4 + reg;
            int b2 = gm >> 11, nseq = gm & (NN - 1);
            int bh = b2 * NHEAD + head;
            if (which == 2) {
#pragma unroll
                for (int n = 0; n < 8; ++n) {
                    int d = n * 16 + l15;
                    Vtp[((size_t)bh * DHEAD + d) * NN + nseq] = f2bf(acc[m][n][reg]);
                }
            } else {
                short* dst = (which == 0 ? Qp : Kp) + ((size_t)bh * NN + nseq) * DHEAD;
#pragma unroll
                for (int p = 0; p < 4; ++p) {
                    int d0 = p * 16 + l15;     // < 64
                    float c = cosT[(size_t)nseq * DHEAD + d0];
                    float s = sinT[(size_t)nseq * DHEAD + d0];
                    float e0 = acc[m][p][reg];
                    float e1 = acc[m][p + 4][reg];
                    dst[d0]      = f2bf((e0 * c - e1 * s) * qsc);
                    dst[d0 + 64] = f2bf((e1 * c + e0 * s) * qsc);
                }
            }
        }
    }
}

// ---------------------------------------------------------------------------
// Output projection GEMM (round-8 verbatim): 256x128 / BK=64 / 8-wave
// 2-phase pipeline, fp32 C epilogue.  Grid (16,16) = 256 blocks = 1/CU.
// ---------------------------------------------------------------------------
__global__ __launch_bounds__(512, 2) void gemm_out_256x128(
    const short* __restrict__ A, const short* __restrict__ Bw,
    float* __restrict__ Cp)
{
    __shared__ __align__(16) short AB[49152];   // 96 KB

    const int tid = threadIdx.x;
    const int w = tid >> 6;
    const int l = tid & 63;
    const int quad = l >> 4;
    const int l15 = l & 15;
    const int bn = blockIdx.x * 128;
    const int bm = blockIdx.y * 256;
    const int K = HIDDEN;

    const short* src[6];
    int ldst[6];
#pragma unroll
    for (int ld = 0; ld < 2; ++ld) {
        int chunk = ld * 512 + tid;
        int row = chunk >> 3;
        int j = (chunk & 7) ^ (row & 7);
        int coff = j * 8;
        src[ld]     = A + (size_t)(bm + row) * K + coff;
        src[2 + ld] = A + (size_t)(bm + 128 + row) * K + coff;
        ldst[ld]     = chunk * 16;
        ldst[2 + ld] = 16384 + chunk * 16;
    }
    {
        int row = tid >> 3;
        int j = (tid & 7) ^ (row & 7);
        int coff = j * 8;
        src[4] = Bw + (size_t)(bn + row) * K + coff;
        src[5] = Bw + (size_t)(bn + 64 + row) * K + coff;
        ldst[4] = 32768 + tid * 16;
        ldst[5] = 32768 + 8192 + tid * 16;
    }

    const int xj = l15 & 7;
    const int jq0 = ((0 * 4 + quad) ^ xj) * 16;
    const int jq1 = ((1 * 4 + quad) ^ xj) * 16;
    const int arow = (w * 32 + l15) * 128;
    const int brow = 32768 + l15 * 128;

    floatx4 acc[2][8];
#pragma unroll
    for (int i = 0; i < 2; ++i)
#pragma unroll
        for (int j = 0; j < 8; ++j) acc[i][j] = (floatx4){0.f, 0.f, 0.f, 0.f};

#pragma unroll
    for (int i = 0; i < 6; ++i)
        gload_lds16(src[i], (short*)((char*)AB + ldst[i]));

#define STAGE(i) gload_lds16(src[i] + kpf, (short*)((char*)AB + ldst[i] + so))
#define MFMA(d, x, y) d = __builtin_amdgcn_mfma_f32_16x16x32_bf16(x, y, d, 0, 0, 0)

    const int NT = K / 64;   // 32
#pragma unroll 1
    for (int t = 0; t < NT; ++t) {
        const int co = (t & 1) * 49152;
        const int so = co ^ 49152;
        int kpf = (t + 1) * 64;
        if (kpf == K) kpf = 0;

        bf16x8 a[2][2], b[4][2];

        // ---------------- P0
        asm volatile("s_waitcnt vmcnt(1)" ::: "memory");
        __builtin_amdgcn_s_barrier();
#pragma unroll
        for (int m = 0; m < 2; ++m) {
            a[m][0] = *(const bf16x8*)((const char*)AB + co + arow + m * 2048 + jq0);
            a[m][1] = *(const bf16x8*)((const char*)AB + co + arow + m * 2048 + jq1);
        }
#pragma unroll
        for (int n = 0; n < 4; ++n) {
            b[n][0] = *(const bf16x8*)((const char*)AB + co + brow + n * 2048 + jq0);
            b[n][1] = *(const bf16x8*)((const char*)AB + co + brow + n * 2048 + jq1);
        }
        STAGE(0); STAGE(1); STAGE(2); STAGE(3); STAGE(4);
        __builtin_amdgcn_s_setprio(1);
#pragma unroll
        for (int m = 0; m < 2; ++m)
#pragma unroll
            for (int n = 0; n < 4; ++n) {
                MFMA(acc[m][n], a[m][0], b[n][0]);
                MFMA(acc[m][n], a[m][1], b[n][1]);
            }
        __builtin_amdgcn_s_setprio(0);

        // ---------------- P1
        asm volatile("s_waitcnt vmcnt(5)" ::: "memory");
        __builtin_amdgcn_s_barrier();
#pragma unroll
        for (int n = 0; n < 4; ++n) {
            b[n][0] = *(const bf16x8*)((const char*)AB + co + brow + (4 + n) * 2048 + jq0);
            b[n][1] = *(const bf16x8*)((const char*)AB + co + brow + (4 + n) * 2048 + jq1);
        }
        STAGE(5);
        __builtin_amdgcn_s_setprio(1);
#pragma unroll
        for (int m = 0; m < 2; ++m)
#pragma unroll
            for (int n = 0; n < 4; ++n) {
                MFMA(acc[m][4 + n], a[m][0], b[n][0]);
                MFMA(acc[m][4 + n], a[m][1], b[n][1]);
            }
        __builtin_amdgcn_s_setprio(0);
    }
#undef STAGE
#undef MFMA

    asm volatile("s_waitcnt vmcnt(0)" ::: "memory");

#pragma unroll
    for (int m = 0; m < 2; ++m) {
#pragma unroll
        for (int reg = 0; reg < 4; ++reg) {
            int row = bm + w * 32 + m * 16 + quad * 4 + reg;
            float* crow = Cp + (size_t)row * HIDDEN + bn;
#pragma unroll
            for (int n = 0; n < 8; ++n)
                crow[n * 16 + l15] = acc[m][n][reg];
        }
    }
}

// ---------------------------------------------------------------------------
// MFMA flash attention R9: swapped QK^T (mfma(K,Q) -> S^T) so each lane
// holds 4 CONSECUTIVE KEYS per n16-block for one query.  Softmax packs with
// v_cvt_pk_bf16_f32 (16 inst, was 32 scalar f2bf) and stores Ps with 8x
// ds_write_b64 (was 32x ds_write_b16).  Ps layout [query][key] (72-col pad)
// makes the b128 A-frag read address-identical to the prior verified read,
// so PV and the output epilogue are unchanged.  ls becomes lane-local
// partials (sum over the lane's 16 keys) reduced once at the end via
// shfl_xor(16/32) + 8 general shfls to redistribute query sums.
// 8 waves x 32 Q-rows, grid (8,32) = 256 blocks = 1/CU.  K/V double-
// buffered, counted drain (R7 structure).
// ---------------------------------------------------------------------------
__global__ __launch_bounds__(512, 2) void attn_mfma8(
    const short* __restrict__ Qb, const short* __restrict__ Kb,
    const short* __restrict__ Vt, short* __restrict__ AOb)
{
    __shared__ __align__(16) short Ks[2][64 * 128];   // 32 KB, swz (s&15)^(row&15)
    __shared__ __align__(16) short Vs[2][128 * 64];   // 32 KB, swz (s&7)^(row&7)
    __shared__ __align__(16) short Ps[8][32][72];     // 36.9 KB bf16 [query][key]

    const int tid = threadIdx.x;       // 0..511
    const int w = tid >> 6;            // 0..7
    const int l = tid & 63;
    const int quad = l >> 4;
    const int l15 = l & 15;
    const int bh = blockIdx.y;
    const int qt = blockIdx.x * 256;

    const short* Qg = Qb + (size_t)bh * NN * DHEAD;
    const short* Kg = Kb + (size_t)bh * NN * DHEAD;
    const short* Vg = Vt + (size_t)bh * DHEAD * NN;

    // ---- Q fragments (registers, whole kernel)
    bf16x8 qf[2][4];
#pragma unroll
    for (int mi = 0; mi < 2; ++mi) {
        const short* qrow = Qg + (size_t)(qt + w * 32 + mi * 16 + l15) * DHEAD + quad * 8;
#pragma unroll
        for (int kc = 0; kc < 4; ++kc) qf[mi][kc] = *(const bf16x8*)(qrow + kc * 32);
    }

    // ---- staging addresses: 2 K-slots + 2 V-slots per thread
    const short* ksrc[2]; int kdst[2];
    const short* vsrc[2]; int vdst[2];
#pragma unroll
    for (int rr = 0; rr < 2; ++rr) {
        int s = rr * 512 + tid;
        {
            int row = s >> 4;
            int j = (s & 15) ^ (row & 15);
            ksrc[rr] = Kg + (size_t)row * DHEAD + j * 8;
            kdst[rr] = s * 8;
        }
        {
            int row = s >> 3;
            int c = (s & 7) ^ (row & 7);
            vsrc[rr] = Vg + (size_t)row * NN + c * 8;
            vdst[rr] = s * 8;
        }
    }

    floatx4 of[2][8];
#pragma unroll
    for (int mi = 0; mi < 2; ++mi)
#pragma unroll
        for (int dc = 0; dc < 8; ++dc) of[mi][dc] = (floatx4){0.f, 0.f, 0.f, 0.f};
    float ls[2] = {0.f, 0.f};          // per-lane partial: query mi*16+l15, this lane's 16 keys

    // ---- prologue: stage tile 0 into buf 0, globalize
#pragma unroll
    for (int rr = 0; rr < 2; ++rr) {
        gload_lds16(ksrc[rr], &Ks[0][0] + kdst[rr]);
        gload_lds16(vsrc[rr], &Vs[0][0] + vdst[rr]);
    }
    asm volatile("s_waitcnt vmcnt(0)" ::: "memory");
    __builtin_amdgcn_s_barrier();

    int cur = 0;
#pragma unroll 1
    for (int kt = 0; kt < NN; kt += 64) {
        // ---- issue next tile's staging into buf[cur^1]
        if (kt + 64 < NN) {
            const int nxt = cur ^ 1;
#pragma unroll
            for (int rr = 0; rr < 2; ++rr) {
                gload_lds16(ksrc[rr] + (size_t)(kt + 64) * DHEAD, &Ks[nxt][0] + kdst[rr]);
                gload_lds16(vsrc[rr] + (kt + 64), &Vs[nxt][0] + vdst[rr]);
            }
        }
        const short* kb = &Ks[cur][0];
        const short* vb = &Vs[cur][0];

        // ---- S^T = K @ Q^T (swapped operands): D[key][q], col=q=l15,
        //      row = key = quad*4+r (+16*n16)
        floatx4 sf[2][4];
#pragma unroll
        for (int n16 = 0; n16 < 4; ++n16) {
            bf16x8 kf[4];
            const short* kbase = kb + (n16 * 16 + l15) * 128;
#pragma unroll
            for (int kc = 0; kc < 4; ++kc)
                kf[kc] = *(const bf16x8*)&kbase[((4 * kc + quad) ^ l15) * 8];
#pragma unroll
            for (int mi = 0; mi < 2; ++mi) {
                floatx4 acc = (floatx4){0.f, 0.f, 0.f, 0.f};
#pragma unroll
                for (int kc = 0; kc < 4; ++kc)
                    acc = __builtin_amdgcn_mfma_f32_16x16x32_bf16(kf[kc], qf[mi][kc], acc, 0, 0, 0);
                sf[mi][n16] = acc;
            }
        }

        // ---- softmax: p = exp2(s); lane-local l partial; pack 4 keys ->
        //      one ds_write_b64 at Ps[query][key]
#pragma unroll
        for (int mi = 0; mi < 2; ++mi)
#pragma unroll
            for (int n16 = 0; n16 < 4; ++n16) {
                float p0 = exp2f(sf[mi][n16][0]);
                float p1 = exp2f(sf[mi][n16][1]);
                float p2 = exp2f(sf[mi][n16][2]);
                float p3 = exp2f(sf[mi][n16][3]);
                ls[mi] += (p0 + p1) + (p2 + p3);
                unsigned u0, u1;
                asm("v_cvt_pk_bf16_f32 %0, %1, %2" : "=v"(u0) : "v"(p0), "v"(p1));
                asm("v_cvt_pk_bf16_f32 %0, %1, %2" : "=v"(u1) : "v"(p2), "v"(p3));
                uint2 uu; uu.x = u0; uu.y = u1;
                *(uint2*)&Ps[w][mi * 16 + l15][n16 * 16 + quad * 4] = uu;
            }

        // ---- P A-frags: address-identical to prior layout (b128, 2-way bank)
        bf16x8 pa[2][2];
#pragma unroll
        for (int mi = 0; mi < 2; ++mi)
#pragma unroll
            for (int kc = 0; kc < 2; ++kc)
                pa[mi][kc] = *(const bf16x8*)&Ps[w][mi * 16 + l15][kc * 32 + quad * 8];

        // ---- O += P @ V
#pragma unroll
        for (int dc = 0; dc < 8; ++dc) {
            int row = dc * 16 + l15;
#pragma unroll
            for (int kc = 0; kc < 2; ++kc) {
                bf16x8 vf = *(const bf16x8*)&vb[row * 64 + (((kc * 4 + quad) ^ (row & 7)) * 8)];
#pragma unroll
                for (int mi = 0; mi < 2; ++mi)
                    of[mi][dc] = __builtin_amdgcn_mfma_f32_16x16x32_bf16(
                                     pa[mi][kc], vf, of[mi][dc], 0, 0, 0);
            }
        }

        // ---- drain next-tile DMA
        asm volatile("s_waitcnt vmcnt(0)" ::: "memory");
        __builtin_amdgcn_s_barrier();
        cur ^= 1;
    }

    // ---- finalize: reduce l across the 4-lane stride-16 group (lane then
    // holds total for query mi*16+l15); redistribute to query quad*4+r rows.
    const int b = bh >> 4, h = bh & (NHEAD - 1);
#pragma unroll
    for (int mi = 0; mi < 2; ++mi) {
        float s = ls[mi];
        s += __shfl_xor(s, 16, 64);
        s += __shfl_xor(s, 32, 64);
#pragma unroll
        for (int r = 0; r < 4; ++r) {
            float sr = __shfl(s, quad * 4 + r, 64);   // lane q*4+r holds query mi*16+(q*4+r)
            float inv = 1.0f / sr;
            int row = qt + w * 32 + mi * 16 + quad * 4 + r;
            short* dst = AOb + ((size_t)(b * NN + row)) * HIDDEN + h * DHEAD;
#pragma unroll
            for (int dc = 0; dc < 8; ++dc)
                dst[dc * 16 + l15] = f2bf(of[mi][dc][r] * inv);
        }
    }
}

// ---------------------------------------------------------------------------
extern "C" void kernel_launch(void* const* d_in, const int* in_sizes, int n_in,
                              void* d_out, int out_size, void* d_ws, size_t ws_size,
                              hipStream_t stream)
{
    const float* hs = (const float*)d_in[0];
    const float* cosT = (const float*)d_in[1];
    const float* sinT = (const float*)d_in[2];
    const float* wqkv = (const float*)d_in[3];
    const float* wo = (const float*)d_in[4];
    float* out = (float*)d_out;

    const size_t N_HS = (size_t)NB * NN * HIDDEN;
    const size_t N_WQ = (size_t)3 * HIDDEN * HIDDEN;
    const size_t N_WO = (size_t)HIDDEN * HIDDEN;
    const size_t SZ = (size_t)NB * NHEAD * NN * DHEAD;

    short* Ahs   = (short*)d_ws;
    short* Wqkvb = Ahs + N_HS;
    short* Wob   = Wqkvb + N_WQ;
    short* Qb    = Wob + N_WO;
    short* Kb    = Qb + SZ;
    short* Vtb   = Kb + SZ;
    short* AOb   = Vtb + SZ;

    {
        int n4a = (int)(N_HS / 4), n4b = (int)(N_WQ / 4), n4c = (int)(N_WO / 4);
        int total = n4a + n4b + n4c;
        cast_bf16_3<<<(total + 255) / 256, 256, 0, stream>>>(
            hs, wqkv, wo, Ahs, Wqkvb, Wob, n4a, n4b, n4c);
    }
    {
        dim3 grid(3 * HIDDEN / 128, NB * NN / 256);   // (48, 16) = 768 = 3x256
        gemm_qkv_256x128<<<grid, 512, 0, stream>>>(
            Ahs, Wqkvb, cosT, sinT, Qb, Kb, Vtb);
    }
    {
        dim3 grid(NN / 256, NB * NHEAD);   // (8, 32) = 256 blocks = 1/CU
        attn_mfma8<<<grid, 512, 0, stream>>>(Qb, Kb, Vtb, AOb);
    }
    {
        dim3 grid(HIDDEN / 128, NB * NN / 256);   // (16, 16) = 256 = 1/CU
        gemm_out_256x128<<<grid, 512, 0, stream>>>(AOb, Wob, out);
    }
}